// Round 5
// baseline (6027.124 us; speedup 1.0000x reference)
//
#include <hip/hip_runtime.h>
#include <hip/hip_bf16.h>

// Problem constants
#define BATCH 32
#define TLEN 512
#define INCH 512
#define HID 512

typedef __bf16 bf16x8 __attribute__((ext_vector_type(8)));
typedef float f32x4 __attribute__((ext_vector_type(4)));
typedef unsigned int u32x4 __attribute__((ext_vector_type(4)));
typedef unsigned short u16x4 __attribute__((ext_vector_type(4)));
using bf16 = __hip_bfloat16;

// ---------------- ws layout (bytes) ----------------
// H32 (tagged h exchange, 2dir*2buf*16384 u32 = 256 KiB) lives at offset 0,
// overlapping XS2: XS2 is dead after gemm_xp, and zero_h_kernel runs after
// gemm_xp on the same stream.
#define OFF_XS2   0ull                      // 16384*512*2 = 16 MiB
#define OFF_WCAT  16777216ull               // 4096*512*2  = 4 MiB
#define OFF_WHHP  20971520ull               // 2*2048*512*2 = 4 MiB
#define OFF_BIAS  25165824ull               // 2*2048*4 = 16 KiB
#define OFF_HBUF  25182208ull               // legacy bf16 h ping-pong (unused)
#define OFF_CTR   25313280ull               // 256 B (legacy, unused)
#define OFF_FLAG  25313536ull               // legacy flags (unused)
#define OFF_XP    25321728ull               // 512*2*2048*32*2 = 128 MiB
#define WS_REQUIRED (25321728ull + 134217728ull)

__device__ __forceinline__ float sigmoid_fast(float x) {
    return 1.f / (1.f + __expf(-x));
}
__device__ __forceinline__ float tanh_fast(float x) {
    float ax = fabsf(x);
    float e = __expf(-2.f * ax);
    float r = (1.f - e) / (1.f + e);
    return copysignf(r, x);
}
__device__ __forceinline__ float bf2f(unsigned short u) {
    unsigned int i = ((unsigned int)u) << 16;
    float f; __builtin_memcpy(&f, &i, 4); return f;
}

__global__ void ws_too_small_kernel(float* out) {
    if (threadIdx.x == 0 && blockIdx.x == 0) out[0] = 12345.0f;
}

// ---------------- pack x -> XS2[(t*32+b)][k] bf16 ----------------
__global__ void pack_x_kernel(const float* __restrict__ x, bf16* __restrict__ XS2) {
    int bx = blockIdx.x;               // 2048 blocks
    int b  = bx >> 6;
    int tt = (bx >> 3) & 7;
    int kt = bx & 7;
    __shared__ float tile[64][65];
    int tid  = threadIdx.x;
    int row2 = tid >> 6;
    int col  = tid & 63;
#pragma unroll
    for (int i = 0; i < 16; ++i) {
        int row = i * 4 + row2;
        int k = kt * 64 + row;
        tile[row][col] = x[((b * 32 + (k >> 4)) * 16 + (k & 15)) * 512 + tt * 64 + col];
    }
    __syncthreads();
#pragma unroll
    for (int i = 0; i < 16; ++i) {
        int trow = i * 4 + row2;
        int t = tt * 64 + trow;
        XS2[(t * 32 + b) * 512 + kt * 64 + col] = __float2bfloat16(tile[col][trow]);
    }
}

// ---------------- pack weights / bias ----------------
// Whhp row permutation: local row lm (0..63 per s) = ul*4 + gate:
// grow = gate*512 + s*16 + ul with gate = lm&3, ul = lm>>2.  With the MFMA
// C-layout row = fq*4+rr this puts all 4 gates of one cell into one lane's acc.
// bias repacked to [dir][s][ul][gate] f32 (float4 per cell).
__global__ void pack_w_kernel(const float* __restrict__ Wih_f, const float* __restrict__ Whh_f,
                              const float* __restrict__ bih_f, const float* __restrict__ bhh_f,
                              const float* __restrict__ Wih_b, const float* __restrict__ Whh_b,
                              const float* __restrict__ bih_b, const float* __restrict__ bhh_b,
                              bf16* __restrict__ Wcat, bf16* __restrict__ Whhp,
                              float* __restrict__ bias) {
    long idx = (long)blockIdx.x * 256 + threadIdx.x;
    if (idx < 262144) {                       // Wcat, 8-wide
        long e = idx * 8;
        int m = (int)(e >> 9), k = (int)(e & 511);
        const float* src = (m < 2048) ? &Wih_f[(long)m * 512 + k]
                                      : &Wih_b[(long)(m - 2048) * 512 + k];
        bf16* dst = &Wcat[e];
#pragma unroll
        for (int j = 0; j < 8; ++j) dst[j] = __float2bfloat16(src[j]);
        return;
    }
    idx -= 262144;
    if (idx < 262144) {                       // Whhp, 8-wide (gate-interleaved rows)
        long e = idx * 8;
        int k  = (int)(e & 511);
        int lm = (int)((e >> 9) & 63);
        int s  = (int)((e >> 15) & 31);
        int dir = (int)(e >> 20);
        int grow = (lm & 3) * 512 + s * 16 + (lm >> 2);
        const float* W = dir ? Whh_b : Whh_f;
        const float* src = &W[(long)grow * 512 + k];
        bf16* dst = &Whhp[e];
#pragma unroll
        for (int j = 0; j < 8; ++j) dst[j] = __float2bfloat16(src[j]);
        return;
    }
    idx -= 262144;
    if (idx < 4096) {                         // bias = b_ih + b_hh, [dir][s][ul][gate]
        int dir  = (int)(idx >> 11);
        int r    = (int)(idx & 2047);
        int s    = r >> 6, ul = (r >> 2) & 15, gate = r & 3;
        int g    = gate * 512 + s * 16 + ul;
        bias[idx] = (dir ? (bih_b[g] + bhh_b[g]) : (bih_f[g] + bhh_f[g]));
        return;
    }
}

// ---------------- zero tagged-h exchange buffer (runs AFTER gemm_xp) ------
// (tag=0, value=0) words = plain zeros; initial h state AND t=0 tag match.
__global__ void zero_h_kernel(unsigned int* __restrict__ H32) {
    int i = (blockIdx.x * 256 + threadIdx.x) * 4;   // 64 blocks -> 65536 u32
    u32x4 z = {0u, 0u, 0u, 0u};
    *(u32x4*)&H32[i] = z;
}

// ---------------- phase 1: XP = Wcat * XS2^T ----------------
// XP[t][dir][s][ul][b][gate] bf16 -> each lstm lane loads its 4 gates as one 8B chunk
__global__ __launch_bounds__(256, 2) void gemm_xp_kernel(const bf16* __restrict__ Wcat,
                                                         const bf16* __restrict__ XS2,
                                                         bf16* __restrict__ XP) {
    int bm = (blockIdx.x & 31) * 128;
    int bn = (blockIdx.x >> 5) * 128;
    __shared__ bf16 lA[128 * 40];
    __shared__ bf16 lB[128 * 40];
    int tid = threadIdx.x;
    int lane = tid & 63, w = tid >> 6;
    int wm = (w & 1) * 64, wn = (w >> 1) * 64;
    int fr = lane & 15, fq = lane >> 4;
    f32x4 acc[4][4] = {};
    int r = tid >> 2, c = tid & 3;
    for (int kt = 0; kt < 16; ++kt) {
        int k0 = kt * 32;
        *(bf16x8*)&lA[r * 40 + c * 8]        = *(const bf16x8*)&Wcat[(long)(bm + r) * 512 + k0 + c * 8];
        *(bf16x8*)&lA[(r + 64) * 40 + c * 8] = *(const bf16x8*)&Wcat[(long)(bm + r + 64) * 512 + k0 + c * 8];
        *(bf16x8*)&lB[r * 40 + c * 8]        = *(const bf16x8*)&XS2[(long)(bn + r) * 512 + k0 + c * 8];
        *(bf16x8*)&lB[(r + 64) * 40 + c * 8] = *(const bf16x8*)&XS2[(long)(bn + r + 64) * 512 + k0 + c * 8];
        __syncthreads();
        bf16x8 af[4], bfm[4];
#pragma unroll
        for (int i = 0; i < 4; ++i) af[i]  = *(const bf16x8*)&lA[(wm + i * 16 + fr) * 40 + fq * 8];
#pragma unroll
        for (int i = 0; i < 4; ++i) bfm[i] = *(const bf16x8*)&lB[(wn + i * 16 + fr) * 40 + fq * 8];
#pragma unroll
        for (int mi = 0; mi < 4; ++mi)
#pragma unroll
            for (int ni = 0; ni < 4; ++ni)
                acc[mi][ni] = __builtin_amdgcn_mfma_f32_16x16x32_bf16(af[mi], bfm[ni], acc[mi][ni], 0, 0, 0);
        __syncthreads();
    }
#pragma unroll
    for (int mi = 0; mi < 4; ++mi) {
#pragma unroll
        for (int rr = 0; rr < 4; ++rr) {
            int m = bm + wm + mi * 16 + fq * 4 + rr;
            int dir = m >> 11, cc = m & 2047;
            int gate = cc >> 9, u = cc & 511, s = u >> 4, ul = u & 15;
#pragma unroll
            for (int ni = 0; ni < 4; ++ni) {
                int n = bn + wn + ni * 16 + fr;
                int t = n >> 5, b = n & 31;
                long off = ((long)(t * 2 + dir) * 32 + s) * 2048 + (long)(ul * 32 + b) * 4 + gate;
                XP[off] = __float2bfloat16(acc[mi][ni][rr]);
            }
        }
    }
}

// ---------------- phase 2: bidirectional LSTM recurrence ----------------
// 64 blocks (dir, s) x 512 threads.  Tagged-word protocol: each h cell is a
// u32 (tag<<16 | bf16), double-buffered H32[dir][buf][s'][b][ul].
//  - producer: each thread stores its OWN cell (tag t+1) fire-and-forget:
//    no gather, no wave-0 serialization, no drain, no flags.
//  - consumer: each thread poll-loads its own 128B slice (sc0/sc1) until all
//    32 tags == t; the poll IS the data load (one coherent trip total).
//  - safety: same induction as the flag protocol at word granularity; a
//    buffer is only overwritten (2 steps later) after every thread
//    device-wide proved (by posting tag t+1) it finished its step-t reads.
// One __syncthreads per step (hsh LDS is double-buffered, pitch 526 keeps
// both staging-write and MFMA-read bank patterns <= 2-way = free).
__global__ __launch_bounds__(512, 1) void lstm_rec_kernel(const bf16* __restrict__ Whhp,
                                                          const bf16* __restrict__ XP,
                                                          const float* __restrict__ bias,
                                                          unsigned int* H32, float* out) {
    int bx = blockIdx.x;
    int dir = bx >> 5, s = bx & 31;
    int tid = threadIdx.x;
    int lane = tid & 63, w = tid >> 6;      // 8 waves
    int mt = w & 3, nt = w >> 2;            // wave -> (ul-quad, batch half)
    int fr = lane & 15, fq = lane >> 4;
    __shared__ float obuf[16][512];         // 32 KiB output chunk (per-thread column)
    __shared__ bf16  hsh[2][32 * 526];      // 2 x 32.9 KiB staged h [b][k], pitch 526

    // persistent A fragments: Whhp[dir][s][mt*16+fr][k] (rows gate-interleaved)
    const bf16* wbase = Whhp + ((long)((dir * 32 + s) * 64 + mt * 16 + fr)) * 512 + fq * 8;
    bf16x8 wA[16];
#pragma unroll
    for (int kt = 0; kt < 16; ++kt) wA[kt] = *(const bf16x8*)(wbase + kt * 32);

    int ul = mt * 4 + fq;                   // hidden sub-index within s
    int b  = nt * 16 + fr;                  // batch
    f32x4 bv = *(const f32x4*)&bias[((dir * 32 + s) * 16 + ul) * 4];
    float cstate = 0.f;

    unsigned int* Hd = H32 + dir * 32768;               // [buf][s'][b][ul]
    const unsigned int* src_base = Hd + tid * 32;       // own 128B poll slice
    unsigned int* st_base = Hd + s * 512 + b * 16 + ul; // own cell
    int sp = tid >> 4;                                  // s' covered by slice
    int b0 = (tid & 15) * 2;                            // first of two b rows
    float* outrow = out + (long)b * 524288 + (long)(dir * 512 + s * 16 + ul) * 512;
    int guard = 1 << 20;

    for (int t = 0; t < TLEN; ++t) {
        int ttime = dir ? (TLEN - 1 - t) : t;
        // xp prefetch (normal cached load): 4 gates of this cell, 8 bytes
        const bf16* xpp = XP + (long)(ttime * 2 + dir) * 65536 + s * 2048 + (ul * 32 + b) * 4;
        u16x4 xv = *(const u16x4*)xpp;

        // poll-load own slice until every word carries tag == t
        const unsigned int* src = src_base + (t & 1) * 16384;
        unsigned int tt = (unsigned int)t;
        u32x4 v0, v1, v2, v3, v4, v5, v6, v7;
        for (;;) {
            asm volatile(
                "global_load_dwordx4 %0, %8, off sc0 sc1\n\t"
                "global_load_dwordx4 %1, %8, off offset:16 sc0 sc1\n\t"
                "global_load_dwordx4 %2, %8, off offset:32 sc0 sc1\n\t"
                "global_load_dwordx4 %3, %8, off offset:48 sc0 sc1\n\t"
                "global_load_dwordx4 %4, %8, off offset:64 sc0 sc1\n\t"
                "global_load_dwordx4 %5, %8, off offset:80 sc0 sc1\n\t"
                "global_load_dwordx4 %6, %8, off offset:96 sc0 sc1\n\t"
                "global_load_dwordx4 %7, %8, off offset:112 sc0 sc1\n\t"
                "s_waitcnt vmcnt(0)"
                : "=&v"(v0), "=&v"(v1), "=&v"(v2), "=&v"(v3),
                  "=&v"(v4), "=&v"(v5), "=&v"(v6), "=&v"(v7)
                : "v"(src) : "memory");
            unsigned int bad;
            bad  = (v0.x >> 16) ^ tt; bad |= (v0.y >> 16) ^ tt;
            bad |= (v0.z >> 16) ^ tt; bad |= (v0.w >> 16) ^ tt;
            bad |= (v1.x >> 16) ^ tt; bad |= (v1.y >> 16) ^ tt;
            bad |= (v1.z >> 16) ^ tt; bad |= (v1.w >> 16) ^ tt;
            bad |= (v2.x >> 16) ^ tt; bad |= (v2.y >> 16) ^ tt;
            bad |= (v2.z >> 16) ^ tt; bad |= (v2.w >> 16) ^ tt;
            bad |= (v3.x >> 16) ^ tt; bad |= (v3.y >> 16) ^ tt;
            bad |= (v3.z >> 16) ^ tt; bad |= (v3.w >> 16) ^ tt;
            bad |= (v4.x >> 16) ^ tt; bad |= (v4.y >> 16) ^ tt;
            bad |= (v4.z >> 16) ^ tt; bad |= (v4.w >> 16) ^ tt;
            bad |= (v5.x >> 16) ^ tt; bad |= (v5.y >> 16) ^ tt;
            bad |= (v5.z >> 16) ^ tt; bad |= (v5.w >> 16) ^ tt;
            bad |= (v6.x >> 16) ^ tt; bad |= (v6.y >> 16) ^ tt;
            bad |= (v6.z >> 16) ^ tt; bad |= (v6.w >> 16) ^ tt;
            bad |= (v7.x >> 16) ^ tt; bad |= (v7.y >> 16) ^ tt;
            bad |= (v7.z >> 16) ^ tt; bad |= (v7.w >> 16) ^ tt;
            if (bad == 0) break;
            if (--guard <= 0) break;
        }

        // strip tags, pack 2 bf16/word, stage into hsh[t&1]
        unsigned int p0  = (v0.x & 0xFFFFu) | (v0.y << 16);
        unsigned int p1  = (v0.z & 0xFFFFu) | (v0.w << 16);
        unsigned int p2  = (v1.x & 0xFFFFu) | (v1.y << 16);
        unsigned int p3  = (v1.z & 0xFFFFu) | (v1.w << 16);
        unsigned int p4  = (v2.x & 0xFFFFu) | (v2.y << 16);
        unsigned int p5  = (v2.z & 0xFFFFu) | (v2.w << 16);
        unsigned int p6  = (v3.x & 0xFFFFu) | (v3.y << 16);
        unsigned int p7  = (v3.z & 0xFFFFu) | (v3.w << 16);
        unsigned int p8  = (v4.x & 0xFFFFu) | (v4.y << 16);
        unsigned int p9  = (v4.z & 0xFFFFu) | (v4.w << 16);
        unsigned int p10 = (v5.x & 0xFFFFu) | (v5.y << 16);
        unsigned int p11 = (v5.z & 0xFFFFu) | (v5.w << 16);
        unsigned int p12 = (v6.x & 0xFFFFu) | (v6.y << 16);
        unsigned int p13 = (v6.z & 0xFFFFu) | (v6.w << 16);
        unsigned int p14 = (v7.x & 0xFFFFu) | (v7.y << 16);
        unsigned int p15 = (v7.z & 0xFFFFu) | (v7.w << 16);
        {
            u32x4 q0 = {p0, p1, p2, p3},   q1 = {p4, p5, p6, p7};
            u32x4 q2 = {p8, p9, p10, p11}, q3 = {p12, p13, p14, p15};
            bf16* d0 = &hsh[t & 1][b0 * 526 + sp * 16];
            bf16* d1 = &hsh[t & 1][(b0 + 1) * 526 + sp * 16];
            *(u32x4*)(d0)     = q0;
            *(u32x4*)(d0 + 8) = q1;
            *(u32x4*)(d1)     = q2;
            *(u32x4*)(d1 + 8) = q3;
        }
        __syncthreads();                    // the ONE barrier per step

        // B fragments from LDS; 4 interleaved MFMA chains over K=512
        f32x4 a0 = {}, a1 = {}, a2 = {}, a3 = {};
        const bf16* hrow = &hsh[t & 1][(nt * 16 + fr) * 526 + fq * 8];
#pragma unroll
        for (int kt = 0; kt < 16; kt += 4) {
            bf16x8 h0 = *(const bf16x8*)(hrow + (kt + 0) * 32);
            bf16x8 h1 = *(const bf16x8*)(hrow + (kt + 1) * 32);
            bf16x8 h2 = *(const bf16x8*)(hrow + (kt + 2) * 32);
            bf16x8 h3 = *(const bf16x8*)(hrow + (kt + 3) * 32);
            a0 = __builtin_amdgcn_mfma_f32_16x16x32_bf16(wA[kt + 0], h0, a0, 0, 0, 0);
            a1 = __builtin_amdgcn_mfma_f32_16x16x32_bf16(wA[kt + 1], h1, a1, 0, 0, 0);
            a2 = __builtin_amdgcn_mfma_f32_16x16x32_bf16(wA[kt + 2], h2, a2, 0, 0, 0);
            a3 = __builtin_amdgcn_mfma_f32_16x16x32_bf16(wA[kt + 3], h3, a3, 0, 0, 0);
        }

        // gates fully in-register: acc[rr] = gate rr of this lane's cell
        float gi = (a0[0] + a1[0]) + (a2[0] + a3[0]) + bv[0] + bf2f(xv.x);
        float gf = (a0[1] + a1[1]) + (a2[1] + a3[1]) + bv[1] + bf2f(xv.y);
        float gg = (a0[2] + a1[2]) + (a2[2] + a3[2]) + bv[2] + bf2f(xv.z);
        float go = (a0[3] + a1[3]) + (a2[3] + a3[3]) + bv[3] + bf2f(xv.w);
        float si = sigmoid_fast(gi), sf = sigmoid_fast(gf), so = sigmoid_fast(go);
        cstate = sf * cstate + si * tanh_fast(gg);
        float h = so * tanh_fast(cstate);

        // own-cell tagged store, fire-and-forget (no drain, no flag)
        bf16 hb16 = __float2bfloat16(h);
        unsigned short hsb; __builtin_memcpy(&hsb, &hb16, 2);
        unsigned int hw = ((unsigned int)(t + 1) << 16) | (unsigned int)hsb;
        unsigned int* haddr = st_base + ((t + 1) & 1) * 16384;
        asm volatile("global_store_dword %0, %1, off sc0 sc1"
                     :: "v"(haddr), "v"(hw) : "memory");

        // output buffering: per-thread obuf column, no barrier needed
        obuf[ttime & 15][tid] = h;
        if ((t & 15) == 15) {
            int tb = ttime & ~15;
            float vals[16];
#pragma unroll
            for (int c = 0; c < 16; ++c) vals[c] = obuf[c][tid];
            float* op = outrow + tb;
#pragma unroll
            for (int c4 = 0; c4 < 4; ++c4)
                *(f32x4*)(op + c4 * 4) = *(f32x4*)&vals[c4 * 4];
        }
    }
}

extern "C" void kernel_launch(void* const* d_in, const int* in_sizes, int n_in,
                              void* d_out, int out_size, void* d_ws, size_t ws_size,
                              hipStream_t stream) {
    const float* x     = (const float*)d_in[0];
    const float* Wih_f = (const float*)d_in[1];
    const float* Whh_f = (const float*)d_in[2];
    const float* bih_f = (const float*)d_in[3];
    const float* bhh_f = (const float*)d_in[4];
    const float* Wih_b = (const float*)d_in[5];
    const float* Whh_b = (const float*)d_in[6];
    const float* bih_b = (const float*)d_in[7];
    const float* bhh_b = (const float*)d_in[8];
    float* out = (float*)d_out;

    if (ws_size < WS_REQUIRED) {
        ws_too_small_kernel<<<1, 64, 0, stream>>>(out);
        return;
    }

    char* ws = (char*)d_ws;
    bf16* XS2  = (bf16*)(ws + OFF_XS2);
    bf16* Wcat = (bf16*)(ws + OFF_WCAT);
    bf16* Whhp = (bf16*)(ws + OFF_WHHP);
    float* bias = (float*)(ws + OFF_BIAS);
    unsigned int* H32 = (unsigned int*)(ws + OFF_XS2);   // overlaps dead XS2
    bf16* XP   = (bf16*)(ws + OFF_XP);

    pack_x_kernel<<<2048, 256, 0, stream>>>(x, XS2);
    pack_w_kernel<<<2065, 256, 0, stream>>>(Wih_f, Whh_f, bih_f, bhh_f,
                                            Wih_b, Whh_b, bih_b, bhh_b,
                                            Wcat, Whhp, bias);
    gemm_xp_kernel<<<4096, 256, 0, stream>>>(Wcat, XS2, XP);
    zero_h_kernel<<<64, 256, 0, stream>>>(H32);          // after gemm_xp: XS2 dead
    lstm_rec_kernel<<<64, 512, 0, stream>>>(Whhp, XP, bias, H32, out);
}

// Round 6
// 5768.785 us; speedup vs baseline: 1.0448x; 1.0448x over previous
//
#include <hip/hip_runtime.h>
#include <hip/hip_bf16.h>

// Problem constants
#define BATCH 32
#define TLEN 512
#define INCH 512
#define HID 512

typedef __bf16 bf16x8 __attribute__((ext_vector_type(8)));
typedef float f32x4 __attribute__((ext_vector_type(4)));
typedef unsigned int u32x4 __attribute__((ext_vector_type(4)));
typedef unsigned short u16x4 __attribute__((ext_vector_type(4)));
using bf16 = __hip_bfloat16;

// ---------------- ws layout (bytes) ----------------
// H32 (tagged h exchange, 2dir*2buf*16384 u32 = 256 KiB) lives at offset 0,
// overlapping XS2: XS2 is dead after gemm_xp, and zero_h_kernel runs after
// gemm_xp on the same stream.
#define OFF_XS2   0ull                      // 16384*512*2 = 16 MiB
#define OFF_WCAT  16777216ull               // 4096*512*2  = 4 MiB
#define OFF_WHHP  20971520ull               // 2*2048*512*2 = 4 MiB
#define OFF_BIAS  25165824ull               // 2*2048*4 = 16 KiB
#define OFF_XP    25321728ull               // 512*2*2048*32*2 = 128 MiB
#define WS_REQUIRED (25321728ull + 134217728ull)

__device__ __forceinline__ float sigmoid_fast(float x) {
    return 1.f / (1.f + __expf(-x));
}
__device__ __forceinline__ float tanh_fast(float x) {
    float ax = fabsf(x);
    float e = __expf(-2.f * ax);
    float r = (1.f - e) / (1.f + e);
    return copysignf(r, x);
}
__device__ __forceinline__ float bf2f(unsigned short u) {
    unsigned int i = ((unsigned int)u) << 16;
    float f; __builtin_memcpy(&f, &i, 4); return f;
}

__global__ void ws_too_small_kernel(float* out) {
    if (threadIdx.x == 0 && blockIdx.x == 0) out[0] = 12345.0f;
}

// ---------------- pack x -> XS2[(t*32+b)][k] bf16 ----------------
__global__ void pack_x_kernel(const float* __restrict__ x, bf16* __restrict__ XS2) {
    int bx = blockIdx.x;               // 2048 blocks
    int b  = bx >> 6;
    int tt = (bx >> 3) & 7;
    int kt = bx & 7;
    __shared__ float tile[64][65];
    int tid  = threadIdx.x;
    int row2 = tid >> 6;
    int col  = tid & 63;
#pragma unroll
    for (int i = 0; i < 16; ++i) {
        int row = i * 4 + row2;
        int k = kt * 64 + row;
        tile[row][col] = x[((b * 32 + (k >> 4)) * 16 + (k & 15)) * 512 + tt * 64 + col];
    }
    __syncthreads();
#pragma unroll
    for (int i = 0; i < 16; ++i) {
        int trow = i * 4 + row2;
        int t = tt * 64 + trow;
        XS2[(t * 32 + b) * 512 + kt * 64 + col] = __float2bfloat16(tile[col][trow]);
    }
}

// ---------------- pack weights / bias ----------------
// Whhp row permutation: local row lm (0..63 per s) = ul*4 + gate:
// grow = gate*512 + s*16 + ul with gate = lm&3, ul = lm>>2.  With the MFMA
// C-layout row = fq*4+rr this puts all 4 gates of one cell into one lane's acc.
// bias repacked to [dir][s][ul][gate] f32 (float4 per cell).
__global__ void pack_w_kernel(const float* __restrict__ Wih_f, const float* __restrict__ Whh_f,
                              const float* __restrict__ bih_f, const float* __restrict__ bhh_f,
                              const float* __restrict__ Wih_b, const float* __restrict__ Whh_b,
                              const float* __restrict__ bih_b, const float* __restrict__ bhh_b,
                              bf16* __restrict__ Wcat, bf16* __restrict__ Whhp,
                              float* __restrict__ bias) {
    long idx = (long)blockIdx.x * 256 + threadIdx.x;
    if (idx < 262144) {                       // Wcat, 8-wide
        long e = idx * 8;
        int m = (int)(e >> 9), k = (int)(e & 511);
        const float* src = (m < 2048) ? &Wih_f[(long)m * 512 + k]
                                      : &Wih_b[(long)(m - 2048) * 512 + k];
        bf16* dst = &Wcat[e];
#pragma unroll
        for (int j = 0; j < 8; ++j) dst[j] = __float2bfloat16(src[j]);
        return;
    }
    idx -= 262144;
    if (idx < 262144) {                       // Whhp, 8-wide (gate-interleaved rows)
        long e = idx * 8;
        int k  = (int)(e & 511);
        int lm = (int)((e >> 9) & 63);
        int s  = (int)((e >> 15) & 31);
        int dir = (int)(e >> 20);
        int grow = (lm & 3) * 512 + s * 16 + (lm >> 2);
        const float* W = dir ? Whh_b : Whh_f;
        const float* src = &W[(long)grow * 512 + k];
        bf16* dst = &Whhp[e];
#pragma unroll
        for (int j = 0; j < 8; ++j) dst[j] = __float2bfloat16(src[j]);
        return;
    }
    idx -= 262144;
    if (idx < 4096) {                         // bias = b_ih + b_hh, [dir][s][ul][gate]
        int dir  = (int)(idx >> 11);
        int r    = (int)(idx & 2047);
        int s    = r >> 6, ul = (r >> 2) & 15, gate = r & 3;
        int g    = gate * 512 + s * 16 + ul;
        bias[idx] = (dir ? (bih_b[g] + bhh_b[g]) : (bih_f[g] + bhh_f[g]));
        return;
    }
}

// ---------------- zero tagged-h exchange buffer (runs AFTER gemm_xp) ------
// (tag=0, value=0) words = plain zeros; initial h state AND t=0 tag match.
__global__ void zero_h_kernel(unsigned int* __restrict__ H32) {
    int i = (blockIdx.x * 256 + threadIdx.x) * 4;   // 64 blocks -> 65536 u32
    u32x4 z = {0u, 0u, 0u, 0u};
    *(u32x4*)&H32[i] = z;
}

// ---------------- phase 1: XP = Wcat * XS2^T ----------------
// XP[t][dir][s][ul][b][gate] bf16 -> each lstm lane loads its 4 gates as one 8B chunk
__global__ __launch_bounds__(256, 2) void gemm_xp_kernel(const bf16* __restrict__ Wcat,
                                                         const bf16* __restrict__ XS2,
                                                         bf16* __restrict__ XP) {
    int bm = (blockIdx.x & 31) * 128;
    int bn = (blockIdx.x >> 5) * 128;
    __shared__ bf16 lA[128 * 40];
    __shared__ bf16 lB[128 * 40];
    int tid = threadIdx.x;
    int lane = tid & 63, w = tid >> 6;
    int wm = (w & 1) * 64, wn = (w >> 1) * 64;
    int fr = lane & 15, fq = lane >> 4;
    f32x4 acc[4][4] = {};
    int r = tid >> 2, c = tid & 3;
    for (int kt = 0; kt < 16; ++kt) {
        int k0 = kt * 32;
        *(bf16x8*)&lA[r * 40 + c * 8]        = *(const bf16x8*)&Wcat[(long)(bm + r) * 512 + k0 + c * 8];
        *(bf16x8*)&lA[(r + 64) * 40 + c * 8] = *(const bf16x8*)&Wcat[(long)(bm + r + 64) * 512 + k0 + c * 8];
        *(bf16x8*)&lB[r * 40 + c * 8]        = *(const bf16x8*)&XS2[(long)(bn + r) * 512 + k0 + c * 8];
        *(bf16x8*)&lB[(r + 64) * 40 + c * 8] = *(const bf16x8*)&XS2[(long)(bn + r + 64) * 512 + k0 + c * 8];
        __syncthreads();
        bf16x8 af[4], bfm[4];
#pragma unroll
        for (int i = 0; i < 4; ++i) af[i]  = *(const bf16x8*)&lA[(wm + i * 16 + fr) * 40 + fq * 8];
#pragma unroll
        for (int i = 0; i < 4; ++i) bfm[i] = *(const bf16x8*)&lB[(wn + i * 16 + fr) * 40 + fq * 8];
#pragma unroll
        for (int mi = 0; mi < 4; ++mi)
#pragma unroll
            for (int ni = 0; ni < 4; ++ni)
                acc[mi][ni] = __builtin_amdgcn_mfma_f32_16x16x32_bf16(af[mi], bfm[ni], acc[mi][ni], 0, 0, 0);
        __syncthreads();
    }
#pragma unroll
    for (int mi = 0; mi < 4; ++mi) {
#pragma unroll
        for (int rr = 0; rr < 4; ++rr) {
            int m = bm + wm + mi * 16 + fq * 4 + rr;
            int dir = m >> 11, cc = m & 2047;
            int gate = cc >> 9, u = cc & 511, s = u >> 4, ul = u & 15;
#pragma unroll
            for (int ni = 0; ni < 4; ++ni) {
                int n = bn + wn + ni * 16 + fr;
                int t = n >> 5, b = n & 31;
                long off = ((long)(t * 2 + dir) * 32 + s) * 2048 + (long)(ul * 32 + b) * 4 + gate;
                XP[off] = __float2bfloat16(acc[mi][ni][rr]);
            }
        }
    }
}

// ---------------- phase 2: bidirectional LSTM recurrence ----------------
// 64 blocks (dir, s) x 512 threads.  Slice-pipelined tagged protocol:
//  - exchange: H32[dir][buf][s'][b][ul] u32 cells = (tag<<16 | h-bf16).
//  - producer: gates -> tagged h into LDS hstage[pbuf] -> per-wave release
//    add on arr[pbuf] -> wave 0 spins arr==8*(use+1), gathers 2 KiB and
//    fires 64x2 dwordx4 sc0/sc1 stores.  NO drain, NO flags: tag rides in
//    each 16B txn; same-lane same-address stores are ordered.
//  - consumer staging: thread tid owns 128B of producer slice sp=tid>>4
//    (rows b0,b0+1): polls until all 32 tags == t (the poll IS the load),
//    strips tags, ds_writes into hsh[buf], release-adds scnt[buf][sp].
//  - MFMA: K-loop spins per slice-pair on scnt (acquire) and multiplies
//    slices as they arrive -- remote latency hides under early-slice MFMAs.
//  - ZERO __syncthreads in the loop; monotonic counters (no resets); safety
//    from the tag induction: tag t+2 on slice sp => producer finished t+1
//    => it saw our tag t+1 => all our waves finished their step-t hsh reads
//    (so hsh[buf]/hstage[pbuf] reuse two steps later is race-free).
//  - every spin is guard-bounded: wrong-output on expiry, never a hang.
__global__ __launch_bounds__(512, 1) void lstm_rec_kernel(const bf16* __restrict__ Whhp,
                                                          const bf16* __restrict__ XP,
                                                          const float* __restrict__ bias,
                                                          unsigned int* H32, float* out) {
    int bx = blockIdx.x;
    int dir = bx >> 5, s = bx & 31;
    int tid = threadIdx.x;
    int lane = tid & 63, w = tid >> 6;      // 8 waves
    int mt = w & 3, nt = w >> 2;            // wave -> (ul-quad, batch half)
    int fr = lane & 15, fq = lane >> 4;
    __shared__ float obuf[16][512];         // 32 KiB output chunk (per-thread column)
    __shared__ bf16  hsh[2][32 * 526];      // 2 x 32.9 KiB staged h [b][k], pitch 526
    __shared__ unsigned int hstage[2][512]; // 2 x 2 KiB tagged h [b][ul]
    __shared__ unsigned int scnt[2][32];    // per-buf per-slice arrival counters
    __shared__ unsigned int arr[2];         // per-buf producer-wave arrivals

    if (tid < 64) scnt[tid >> 5][tid & 31] = 0u;
    if (tid < 2)  arr[tid] = 0u;

    // persistent A fragments: Whhp[dir][s][mt*16+fr][k] (rows gate-interleaved)
    const bf16* wbase = Whhp + ((long)((dir * 32 + s) * 64 + mt * 16 + fr)) * 512 + fq * 8;
    bf16x8 wA[16];
#pragma unroll
    for (int kt = 0; kt < 16; ++kt) wA[kt] = *(const bf16x8*)(wbase + kt * 32);

    int ul = mt * 4 + fq;                   // hidden sub-index within s
    int b  = nt * 16 + fr;                  // batch
    f32x4 bv = *(const f32x4*)&bias[((dir * 32 + s) * 16 + ul) * 4];
    float cstate = 0.f;

    unsigned int* Hd = H32 + dir * 32768;               // [buf][s'][b][ul]
    int sp = tid >> 4;                                  // staged producer slice
    int b0 = (tid & 15) * 2;                            // two b-rows of 128B
    const unsigned int* src_base = Hd + sp * 512 + b0 * 16;
    unsigned int* st_base = Hd + s * 512 + lane * 8;    // wave-0 store: 8 u32/lane
    float* outrow = out + (long)b * 524288 + (long)(dir * 512 + s * 16 + ul) * 512;
    int guard = 1 << 22;

    __syncthreads();                        // counters visible; loop is barrier-free

    for (int t = 0; t < TLEN; ++t) {
        int ttime = dir ? (TLEN - 1 - t) : t;
        int buf = t & 1;
        // xp prefetch (normal cached load): 4 gates of this cell, 8 bytes
        const bf16* xpp = XP + (long)(ttime * 2 + dir) * 65536 + s * 2048 + (ul * 32 + b) * 4;
        u16x4 xv = *(const u16x4*)xpp;

        // ---- staging: poll own 128B of slice sp until all 32 tags == t ----
        const unsigned int* src = src_base + buf * 16384;
        unsigned int tt = (unsigned int)t;
        u32x4 v0, v1, v2, v3, v4, v5, v6, v7;
        for (;;) {
            asm volatile(
                "global_load_dwordx4 %0, %8, off sc0 sc1\n\t"
                "global_load_dwordx4 %1, %8, off offset:16 sc0 sc1\n\t"
                "global_load_dwordx4 %2, %8, off offset:32 sc0 sc1\n\t"
                "global_load_dwordx4 %3, %8, off offset:48 sc0 sc1\n\t"
                "global_load_dwordx4 %4, %8, off offset:64 sc0 sc1\n\t"
                "global_load_dwordx4 %5, %8, off offset:80 sc0 sc1\n\t"
                "global_load_dwordx4 %6, %8, off offset:96 sc0 sc1\n\t"
                "global_load_dwordx4 %7, %8, off offset:112 sc0 sc1\n\t"
                "s_waitcnt vmcnt(0)"
                : "=&v"(v0), "=&v"(v1), "=&v"(v2), "=&v"(v3),
                  "=&v"(v4), "=&v"(v5), "=&v"(v6), "=&v"(v7)
                : "v"(src) : "memory");
            unsigned int bad;
            bad  = (v0.x >> 16) ^ tt; bad |= (v0.y >> 16) ^ tt;
            bad |= (v0.z >> 16) ^ tt; bad |= (v0.w >> 16) ^ tt;
            bad |= (v1.x >> 16) ^ tt; bad |= (v1.y >> 16) ^ tt;
            bad |= (v1.z >> 16) ^ tt; bad |= (v1.w >> 16) ^ tt;
            bad |= (v2.x >> 16) ^ tt; bad |= (v2.y >> 16) ^ tt;
            bad |= (v2.z >> 16) ^ tt; bad |= (v2.w >> 16) ^ tt;
            bad |= (v3.x >> 16) ^ tt; bad |= (v3.y >> 16) ^ tt;
            bad |= (v3.z >> 16) ^ tt; bad |= (v3.w >> 16) ^ tt;
            bad |= (v4.x >> 16) ^ tt; bad |= (v4.y >> 16) ^ tt;
            bad |= (v4.z >> 16) ^ tt; bad |= (v4.w >> 16) ^ tt;
            bad |= (v5.x >> 16) ^ tt; bad |= (v5.y >> 16) ^ tt;
            bad |= (v5.z >> 16) ^ tt; bad |= (v5.w >> 16) ^ tt;
            bad |= (v6.x >> 16) ^ tt; bad |= (v6.y >> 16) ^ tt;
            bad |= (v6.z >> 16) ^ tt; bad |= (v6.w >> 16) ^ tt;
            bad |= (v7.x >> 16) ^ tt; bad |= (v7.y >> 16) ^ tt;
            bad |= (v7.z >> 16) ^ tt; bad |= (v7.w >> 16) ^ tt;
            if (bad == 0) break;
            if (--guard <= 0) break;
        }
        // strip tags, pack 2 bf16/word, stage rows b0,b0+1 into hsh[buf]
        {
            unsigned int p0  = (v0.x & 0xFFFFu) | (v0.y << 16);
            unsigned int p1  = (v0.z & 0xFFFFu) | (v0.w << 16);
            unsigned int p2  = (v1.x & 0xFFFFu) | (v1.y << 16);
            unsigned int p3  = (v1.z & 0xFFFFu) | (v1.w << 16);
            unsigned int p4  = (v2.x & 0xFFFFu) | (v2.y << 16);
            unsigned int p5  = (v2.z & 0xFFFFu) | (v2.w << 16);
            unsigned int p6  = (v3.x & 0xFFFFu) | (v3.y << 16);
            unsigned int p7  = (v3.z & 0xFFFFu) | (v3.w << 16);
            unsigned int p8  = (v4.x & 0xFFFFu) | (v4.y << 16);
            unsigned int p9  = (v4.z & 0xFFFFu) | (v4.w << 16);
            unsigned int p10 = (v5.x & 0xFFFFu) | (v5.y << 16);
            unsigned int p11 = (v5.z & 0xFFFFu) | (v5.w << 16);
            unsigned int p12 = (v6.x & 0xFFFFu) | (v6.y << 16);
            unsigned int p13 = (v6.z & 0xFFFFu) | (v6.w << 16);
            unsigned int p14 = (v7.x & 0xFFFFu) | (v7.y << 16);
            unsigned int p15 = (v7.z & 0xFFFFu) | (v7.w << 16);
            u32x4 q0 = {p0, p1, p2, p3},   q1 = {p4, p5, p6, p7};
            u32x4 q2 = {p8, p9, p10, p11}, q3 = {p12, p13, p14, p15};
            bf16* d0 = &hsh[buf][b0 * 526 + sp * 16];
            bf16* d1 = &hsh[buf][(b0 + 1) * 526 + sp * 16];
            *(u32x4*)(d0)     = q0;
            *(u32x4*)(d0 + 8) = q1;
            *(u32x4*)(d1)     = q2;
            *(u32x4*)(d1 + 8) = q3;
        }
        __hip_atomic_fetch_add(&scnt[buf][sp], 1u, __ATOMIC_RELEASE,
                               __HIP_MEMORY_SCOPE_WORKGROUP);

        // ---- MFMA: consume slice-pairs as they arrive ----
        unsigned int starget = 16u * ((unsigned int)(t >> 1) + 1u);
        f32x4 a0 = {}, a1 = {}, a2 = {}, a3 = {};
        const bf16* hrow = &hsh[buf][(nt * 16 + fr) * 526 + fq * 8];
#pragma unroll
        for (int kt = 0; kt < 16; ++kt) {
            while (__hip_atomic_load(&scnt[buf][2 * kt], __ATOMIC_ACQUIRE,
                                     __HIP_MEMORY_SCOPE_WORKGROUP) < starget) {
                if (--guard <= 0) break;
            }
            while (__hip_atomic_load(&scnt[buf][2 * kt + 1], __ATOMIC_ACQUIRE,
                                     __HIP_MEMORY_SCOPE_WORKGROUP) < starget) {
                if (--guard <= 0) break;
            }
            bf16x8 hB = *(const bf16x8*)(hrow + kt * 32);
            if ((kt & 3) == 0)      a0 = __builtin_amdgcn_mfma_f32_16x16x32_bf16(wA[kt], hB, a0, 0, 0, 0);
            else if ((kt & 3) == 1) a1 = __builtin_amdgcn_mfma_f32_16x16x32_bf16(wA[kt], hB, a1, 0, 0, 0);
            else if ((kt & 3) == 2) a2 = __builtin_amdgcn_mfma_f32_16x16x32_bf16(wA[kt], hB, a2, 0, 0, 0);
            else                    a3 = __builtin_amdgcn_mfma_f32_16x16x32_bf16(wA[kt], hB, a3, 0, 0, 0);
        }

        // gates fully in-register: acc[rr] = gate rr of this lane's cell
        float gi = (a0[0] + a1[0]) + (a2[0] + a3[0]) + bv[0] + bf2f(xv.x);
        float gf = (a0[1] + a1[1]) + (a2[1] + a3[1]) + bv[1] + bf2f(xv.y);
        float gg = (a0[2] + a1[2]) + (a2[2] + a3[2]) + bv[2] + bf2f(xv.z);
        float go = (a0[3] + a1[3]) + (a2[3] + a3[3]) + bv[3] + bf2f(xv.w);
        float si = sigmoid_fast(gi), sf = sigmoid_fast(gf), so = sigmoid_fast(go);
        cstate = sf * cstate + si * tanh_fast(gg);
        float h = so * tanh_fast(cstate);

        // ---- post: tagged h -> hstage; wave 0 publishes 2 KiB, no drain ----
        int pbuf = (t + 1) & 1;
        bf16 hb16 = __float2bfloat16(h);
        unsigned short hsb; __builtin_memcpy(&hsb, &hb16, 2);
        unsigned int hw = ((unsigned int)(t + 1) << 16) | (unsigned int)hsb;
        hstage[pbuf][b * 16 + ul] = hw;
        if (lane == 0)
            __hip_atomic_fetch_add(&arr[pbuf], 1u, __ATOMIC_RELEASE,
                                   __HIP_MEMORY_SCOPE_WORKGROUP);
        if (w == 0) {
            unsigned int atarget = 8u * ((unsigned int)(t >> 1) + 1u);
            while (__hip_atomic_load(&arr[pbuf], __ATOMIC_ACQUIRE,
                                     __HIP_MEMORY_SCOPE_WORKGROUP) < atarget) {
                if (--guard <= 0) break;
            }
            u32x4 g0 = *(const u32x4*)&hstage[pbuf][lane * 8];
            u32x4 g1 = *(const u32x4*)&hstage[pbuf][lane * 8 + 4];
            unsigned int* dst = st_base + pbuf * 16384;
            asm volatile(
                "global_store_dwordx4 %0, %2, off sc0 sc1\n\t"
                "global_store_dwordx4 %1, %3, off sc0 sc1"
                :: "v"(dst), "v"(dst + 4), "v"(g0), "v"(g1) : "memory");
        }

        // output buffering: per-thread obuf column, no barrier needed
        obuf[ttime & 15][tid] = h;
        if ((t & 15) == 15) {
            int tb = ttime & ~15;
            float vals[16];
#pragma unroll
            for (int c = 0; c < 16; ++c) vals[c] = obuf[c][tid];
            float* op = outrow + tb;
#pragma unroll
            for (int c4 = 0; c4 < 4; ++c4)
                *(f32x4*)(op + c4 * 4) = *(f32x4*)&vals[c4 * 4];
        }
    }
}

extern "C" void kernel_launch(void* const* d_in, const int* in_sizes, int n_in,
                              void* d_out, int out_size, void* d_ws, size_t ws_size,
                              hipStream_t stream) {
    const float* x     = (const float*)d_in[0];
    const float* Wih_f = (const float*)d_in[1];
    const float* Whh_f = (const float*)d_in[2];
    const float* bih_f = (const float*)d_in[3];
    const float* bhh_f = (const float*)d_in[4];
    const float* Wih_b = (const float*)d_in[5];
    const float* Whh_b = (const float*)d_in[6];
    const float* bih_b = (const float*)d_in[7];
    const float* bhh_b = (const float*)d_in[8];
    float* out = (float*)d_out;

    if (ws_size < WS_REQUIRED) {
        ws_too_small_kernel<<<1, 64, 0, stream>>>(out);
        return;
    }

    char* ws = (char*)d_ws;
    bf16* XS2  = (bf16*)(ws + OFF_XS2);
    bf16* Wcat = (bf16*)(ws + OFF_WCAT);
    bf16* Whhp = (bf16*)(ws + OFF_WHHP);
    float* bias = (float*)(ws + OFF_BIAS);
    unsigned int* H32 = (unsigned int*)(ws + OFF_XS2);   // overlaps dead XS2
    bf16* XP   = (bf16*)(ws + OFF_XP);

    pack_x_kernel<<<2048, 256, 0, stream>>>(x, XS2);
    pack_w_kernel<<<2065, 256, 0, stream>>>(Wih_f, Whh_f, bih_f, bhh_f,
                                            Wih_b, Whh_b, bih_b, bhh_b,
                                            Wcat, Whhp, bias);
    gemm_xp_kernel<<<4096, 256, 0, stream>>>(Wcat, XS2, XP);
    zero_h_kernel<<<64, 256, 0, stream>>>(H32);          // after gemm_xp: XS2 dead
    lstm_rec_kernel<<<64, 512, 0, stream>>>(Whhp, XP, bias, H32, out);
}

// Round 8
// 2991.089 us; speedup vs baseline: 2.0150x; 1.9287x over previous
//
#include <hip/hip_runtime.h>
#include <hip/hip_bf16.h>

// Problem constants
#define BATCH 32
#define TLEN 512
#define INCH 512
#define HID 512

typedef __bf16 bf16x8 __attribute__((ext_vector_type(8)));
typedef float f32x4 __attribute__((ext_vector_type(4)));
typedef unsigned short u16x4 __attribute__((ext_vector_type(4)));
using bf16 = __hip_bfloat16;

// ---------------- ws layout (bytes) ----------------
#define OFF_XS2   0ull                      // 16384*512*2 = 16 MiB
#define OFF_WCAT  16777216ull               // 4096*512*2  = 4 MiB
#define OFF_WHHP  20971520ull               // 2*2048*512*2 = 4 MiB
#define OFF_BIAS  25165824ull               // 2*2048*4 = 16 KiB
#define OFF_HBUF  25182208ull               // 2dir*2buf*32*512*2 = 128 KiB
#define OFF_CTR   25313280ull               // 256 B (legacy, unused)
#define OFF_FLAG  25313536ull               // 64 flags * 128 B = 8 KiB
#define OFF_XP    25321728ull               // 512*2*2048*32*2 = 128 MiB
#define WS_REQUIRED (25321728ull + 134217728ull)

__device__ __forceinline__ float sigmoid_fast(float x) {
    return 1.f / (1.f + __expf(-x));
}
__device__ __forceinline__ float tanh_fast(float x) {
    float ax = fabsf(x);
    float e = __expf(-2.f * ax);
    float r = (1.f - e) / (1.f + e);
    return copysignf(r, x);
}
__device__ __forceinline__ float bf2f(unsigned short u) {
    unsigned int i = ((unsigned int)u) << 16;
    float f; __builtin_memcpy(&f, &i, 4); return f;
}

__global__ void ws_too_small_kernel(float* out) {
    if (threadIdx.x == 0 && blockIdx.x == 0) out[0] = 12345.0f;
}

// ---------------- pack x -> XS2[(t*32+b)][k] bf16 ----------------
__global__ void pack_x_kernel(const float* __restrict__ x, bf16* __restrict__ XS2) {
    int bx = blockIdx.x;               // 2048 blocks
    int b  = bx >> 6;
    int tt = (bx >> 3) & 7;
    int kt = bx & 7;
    __shared__ float tile[64][65];
    int tid  = threadIdx.x;
    int row2 = tid >> 6;
    int col  = tid & 63;
#pragma unroll
    for (int i = 0; i < 16; ++i) {
        int row = i * 4 + row2;
        int k = kt * 64 + row;
        tile[row][col] = x[((b * 32 + (k >> 4)) * 16 + (k & 15)) * 512 + tt * 64 + col];
    }
    __syncthreads();
#pragma unroll
    for (int i = 0; i < 16; ++i) {
        int trow = i * 4 + row2;
        int t = tt * 64 + trow;
        XS2[(t * 32 + b) * 512 + kt * 64 + col] = __float2bfloat16(tile[col][trow]);
    }
}

// ---------------- pack weights / bias / zero-init ----------------
// Whhp row permutation: local row lm (0..63 per s) = ul*4 + gate:
// grow = gate*512 + s*16 + ul with gate = lm&3, ul = lm>>2.  With the MFMA
// C-layout row = fq*4+rr this puts all 4 gates of one cell into one lane's acc.
// bias repacked to [dir][s][ul][gate] f32 (float4 per cell).
__global__ void pack_w_kernel(const float* __restrict__ Wih_f, const float* __restrict__ Whh_f,
                              const float* __restrict__ bih_f, const float* __restrict__ bhh_f,
                              const float* __restrict__ Wih_b, const float* __restrict__ Whh_b,
                              const float* __restrict__ bih_b, const float* __restrict__ bhh_b,
                              bf16* __restrict__ Wcat, bf16* __restrict__ Whhp,
                              float* __restrict__ bias, unsigned int* __restrict__ hbuf32,
                              unsigned int* __restrict__ ctr, unsigned int* __restrict__ flags) {
    long idx = (long)blockIdx.x * 256 + threadIdx.x;
    if (idx < 262144) {                       // Wcat, 8-wide
        long e = idx * 8;
        int m = (int)(e >> 9), k = (int)(e & 511);
        const float* src = (m < 2048) ? &Wih_f[(long)m * 512 + k]
                                      : &Wih_b[(long)(m - 2048) * 512 + k];
        bf16* dst = &Wcat[e];
#pragma unroll
        for (int j = 0; j < 8; ++j) dst[j] = __float2bfloat16(src[j]);
        return;
    }
    idx -= 262144;
    if (idx < 262144) {                       // Whhp, 8-wide (gate-interleaved rows)
        long e = idx * 8;
        int k  = (int)(e & 511);
        int lm = (int)((e >> 9) & 63);
        int s  = (int)((e >> 15) & 31);
        int dir = (int)(e >> 20);
        int grow = (lm & 3) * 512 + s * 16 + (lm >> 2);
        const float* W = dir ? Whh_b : Whh_f;
        const float* src = &W[(long)grow * 512 + k];
        bf16* dst = &Whhp[e];
#pragma unroll
        for (int j = 0; j < 8; ++j) dst[j] = __float2bfloat16(src[j]);
        return;
    }
    idx -= 262144;
    if (idx < 4096) {                         // bias = b_ih + b_hh, [dir][s][ul][gate]
        int dir  = (int)(idx >> 11);
        int r    = (int)(idx & 2047);
        int s    = r >> 6, ul = (r >> 2) & 15, gate = r & 3;
        int g    = gate * 512 + s * 16 + ul;
        bias[idx] = (dir ? (bih_b[g] + bhh_b[g]) : (bih_f[g] + bhh_f[g]));
        return;
    }
    idx -= 4096;
    if (idx < 32768) { hbuf32[idx] = 0u; return; }  // zero h ping-pong (both dirs)
    idx -= 32768;
    if (idx < 64) { ctr[idx] = 0u; return; }
    idx -= 64;
    if (idx < 2048) { flags[idx] = 0u; return; }    // zero epoch flags
}

// ---------------- phase 1: XP = Wcat * XS2^T ----------------
// XP[t][dir][s][ul][b][gate] bf16 -> each lstm lane loads its 4 gates as one 8B chunk
__global__ __launch_bounds__(256, 2) void gemm_xp_kernel(const bf16* __restrict__ Wcat,
                                                         const bf16* __restrict__ XS2,
                                                         bf16* __restrict__ XP) {
    int bm = (blockIdx.x & 31) * 128;
    int bn = (blockIdx.x >> 5) * 128;
    __shared__ bf16 lA[128 * 40];
    __shared__ bf16 lB[128 * 40];
    int tid = threadIdx.x;
    int lane = tid & 63, w = tid >> 6;
    int wm = (w & 1) * 64, wn = (w >> 1) * 64;
    int fr = lane & 15, fq = lane >> 4;
    f32x4 acc[4][4] = {};
    int r = tid >> 2, c = tid & 3;
    for (int kt = 0; kt < 16; ++kt) {
        int k0 = kt * 32;
        *(bf16x8*)&lA[r * 40 + c * 8]        = *(const bf16x8*)&Wcat[(long)(bm + r) * 512 + k0 + c * 8];
        *(bf16x8*)&lA[(r + 64) * 40 + c * 8] = *(const bf16x8*)&Wcat[(long)(bm + r + 64) * 512 + k0 + c * 8];
        *(bf16x8*)&lB[r * 40 + c * 8]        = *(const bf16x8*)&XS2[(long)(bn + r) * 512 + k0 + c * 8];
        *(bf16x8*)&lB[(r + 64) * 40 + c * 8] = *(const bf16x8*)&XS2[(long)(bn + r + 64) * 512 + k0 + c * 8];
        __syncthreads();
        bf16x8 af[4], bfm[4];
#pragma unroll
        for (int i = 0; i < 4; ++i) af[i]  = *(const bf16x8*)&lA[(wm + i * 16 + fr) * 40 + fq * 8];
#pragma unroll
        for (int i = 0; i < 4; ++i) bfm[i] = *(const bf16x8*)&lB[(wn + i * 16 + fr) * 40 + fq * 8];
#pragma unroll
        for (int mi = 0; mi < 4; ++mi)
#pragma unroll
            for (int ni = 0; ni < 4; ++ni)
                acc[mi][ni] = __builtin_amdgcn_mfma_f32_16x16x32_bf16(af[mi], bfm[ni], acc[mi][ni], 0, 0, 0);
        __syncthreads();
    }
#pragma unroll
    for (int mi = 0; mi < 4; ++mi) {
#pragma unroll
        for (int rr = 0; rr < 4; ++rr) {
            int m = bm + wm + mi * 16 + fq * 4 + rr;
            int dir = m >> 11, cc = m & 2047;
            int gate = cc >> 9, u = cc & 511, s = u >> 4, ul = u & 15;
#pragma unroll
            for (int ni = 0; ni < 4; ++ni) {
                int n = bn + wn + ni * 16 + fr;
                int t = n >> 5, b = n & 31;
                long off = ((long)(t * 2 + dir) * 32 + s) * 2048 + (long)(ul * 32 + b) * 4 + gate;
                XP[off] = __float2bfloat16(acc[mi][ni][rr]);
            }
        }
    }
}

// ---------------- phase 2: bidirectional LSTM recurrence ----------------
// 32 blocks (one per s) x 512 threads; each block runs BOTH directions,
// alternating F-phase / B-phase per step.  While a block computes B(t), the
// peers' f-flags(t+1) propagate -> the F(t+1) poll succeeds immediately;
// b-flags get a full F-phase + B-phase of slack.  Sync latency (detect +
// propagation + straggler drift) hides under the other direction's compute.
// Per-direction mechanics are IDENTICAL to the verified round-4 kernel:
// block-contiguous H[dir][buf][s][b][ul], sc0/sc1 dwordx4 staging, wave-0
// contiguous 1 KiB store + vmcnt(0) drain + relaxed flag post on padded
// lines, all-wave flag poll (r3-verified).  No atomics anywhere.
__global__ __launch_bounds__(512, 1) void lstm_rec_kernel(const bf16* __restrict__ Whhp,
                                                          const bf16* __restrict__ XP,
                                                          const float* __restrict__ bias,
                                                          bf16* hbuf, float* out,
                                                          unsigned int* flags) {
    int s = blockIdx.x;                     // 0..31
    int tid = threadIdx.x;
    int lane = tid & 63, w = tid >> 6;      // 8 waves
    int mt = w & 3, nt = w >> 2;            // wave -> (ul-quad, batch half)
    int fr = lane & 15, fq = lane >> 4;
    __shared__ float obuf[2][16][512];      // 64 KiB output chunks (per-thread column)
    __shared__ bf16  hstage[2][BATCH * 16]; // 2 x 1 KiB h slice [b][ul]
    __shared__ bf16  hsh[2][32 * 520];      // 2 x 32.5 KiB staged h [b][k], pitch 520

    // persistent A fragments for both dirs (rows gate-interleaved)
    const bf16* wbf = Whhp + ((long)((0 * 32 + s) * 64 + mt * 16 + fr)) * 512 + fq * 8;
    const bf16* wbb = Whhp + ((long)((1 * 32 + s) * 64 + mt * 16 + fr)) * 512 + fq * 8;
    bf16x8 wAf[16], wAb[16];
#pragma unroll
    for (int kt = 0; kt < 16; ++kt) wAf[kt] = *(const bf16x8*)(wbf + kt * 32);
#pragma unroll
    for (int kt = 0; kt < 16; ++kt) wAb[kt] = *(const bf16x8*)(wbb + kt * 32);

    int ul = mt * 4 + fq;                   // hidden sub-index within s
    int b  = nt * 16 + fr;                  // batch
    f32x4 bvf = *(const f32x4*)&bias[((0 * 32 + s) * 16 + ul) * 4];
    f32x4 bvb = *(const f32x4*)&bias[((1 * 32 + s) * 16 + ul) * 4];
    float csf = 0.f, csb = 0.f;

    // H[dir][buf][s'][b][ul]: per dir 2 buffers of 16384 elems (32 KiB)
    bf16* hb_f = hbuf;
    bf16* hb_b = hbuf + 2 * 16384;
    unsigned int* myflag_f = flags + (0 * 32 + s) * 32;   // own 128-B lines
    unsigned int* myflag_b = flags + (1 * 32 + s) * 32;
    const unsigned int* pollf = flags + (0 * 32 + (lane & 31)) * 32;
    const unsigned int* pollb = flags + (1 * 32 + (lane & 31)) * 32;
    float* outrow_f = out + (long)b * 524288 + (long)(0 * 512 + s * 16 + ul) * 512;
    float* outrow_b = out + (long)b * 524288 + (long)(1 * 512 + s * 16 + ul) * 512;
    // staging mapping (r4): thread tid loads 4 consecutive 16B chunks at byte
    // tid*64; chunk c=(4*tid+j) -> (s'=c>>6, bb=(c>>1)&31, uh=c&1) ->
    // lds elem off = bb*520 + s'*16 + uh*8
    int c0 = tid * 4;
    int sb0 = ((c0 >> 1) & 31) * 520 + (c0 >> 6) * 16;        // chunks 0,1
    int sb1 = (((c0 + 2) >> 1) & 31) * 520 + (c0 >> 6) * 16;  // chunks 2,3
    int guard = 1 << 21;

    for (int t = 0; t < TLEN; ++t) {
        // ================= F phase (dir 0, ttime = t) =================
        {
            int ttime = t;
            const bf16* xpp = XP + (long)(ttime * 2 + 0) * 65536 + s * 2048 + (ul * 32 + b) * 4;
            u16x4 xv = *(const u16x4*)xpp;

            if (t > 0) {
                unsigned int target = (unsigned int)t;
                for (;;) {
                    unsigned int v = __hip_atomic_load(pollf, __ATOMIC_RELAXED,
                                                       __HIP_MEMORY_SCOPE_AGENT);
                    if (__all(v >= target)) break;
                    if (--guard <= 0) break;
                }
            }
            // stage h_f(t) (device-coherent, coalesced 64B/thread) into hsh[0]
            {
                const bf16* src = hb_f + (long)(t & 1) * 16384 + (long)tid * 32;
                f32x4 v0, v1, v2, v3;
                asm volatile(
                    "global_load_dwordx4 %0, %4, off sc0 sc1\n\t"
                    "global_load_dwordx4 %1, %4, off offset:16 sc0 sc1\n\t"
                    "global_load_dwordx4 %2, %4, off offset:32 sc0 sc1\n\t"
                    "global_load_dwordx4 %3, %4, off offset:48 sc0 sc1\n\t"
                    "s_waitcnt vmcnt(0)"
                    : "=&v"(v0), "=&v"(v1), "=&v"(v2), "=&v"(v3)
                    : "v"(src) : "memory");
                bf16* d0 = &hsh[0][sb0];
                bf16* d1 = &hsh[0][sb1];
                *(f32x4*)(d0)     = v0;
                *(f32x4*)(d0 + 8) = v1;
                *(f32x4*)(d1)     = v2;
                *(f32x4*)(d1 + 8) = v3;
            }
            __syncthreads();

            f32x4 a0 = {}, a1 = {}, a2 = {}, a3 = {};
            const bf16* hrow = &hsh[0][(nt * 16 + fr) * 520 + fq * 8];
#pragma unroll
            for (int kt = 0; kt < 16; kt += 4) {
                bf16x8 h0 = *(const bf16x8*)(hrow + (kt + 0) * 32);
                bf16x8 h1 = *(const bf16x8*)(hrow + (kt + 1) * 32);
                bf16x8 h2 = *(const bf16x8*)(hrow + (kt + 2) * 32);
                bf16x8 h3 = *(const bf16x8*)(hrow + (kt + 3) * 32);
                a0 = __builtin_amdgcn_mfma_f32_16x16x32_bf16(wAf[kt + 0], h0, a0, 0, 0, 0);
                a1 = __builtin_amdgcn_mfma_f32_16x16x32_bf16(wAf[kt + 1], h1, a1, 0, 0, 0);
                a2 = __builtin_amdgcn_mfma_f32_16x16x32_bf16(wAf[kt + 2], h2, a2, 0, 0, 0);
                a3 = __builtin_amdgcn_mfma_f32_16x16x32_bf16(wAf[kt + 3], h3, a3, 0, 0, 0);
            }
            float gi = (a0[0] + a1[0]) + (a2[0] + a3[0]) + bvf[0] + bf2f(xv.x);
            float gf = (a0[1] + a1[1]) + (a2[1] + a3[1]) + bvf[1] + bf2f(xv.y);
            float gg = (a0[2] + a1[2]) + (a2[2] + a3[2]) + bvf[2] + bf2f(xv.z);
            float go = (a0[3] + a1[3]) + (a2[3] + a3[3]) + bvf[3] + bf2f(xv.w);
            float si = sigmoid_fast(gi), sf = sigmoid_fast(gf), so = sigmoid_fast(go);
            csf = sf * csf + si * tanh_fast(gg);
            float h = so * tanh_fast(csf);

            hstage[0][b * 16 + ul] = __float2bfloat16(h);
            obuf[0][ttime & 15][tid] = h;
            __syncthreads();

            if (w == 0) {
                f32x4 hv = *(const f32x4*)&hstage[0][lane * 8];
                bf16* dst = hb_f + (long)((t + 1) & 1) * 16384 + s * 512 + lane * 8;
                asm volatile("global_store_dwordx4 %0, %1, off sc0 sc1"
                             :: "v"(dst), "v"(hv) : "memory");
                asm volatile("s_waitcnt vmcnt(0)" ::: "memory");
                if (lane == 0)
                    __hip_atomic_store(myflag_f, (unsigned int)(t + 1), __ATOMIC_RELAXED,
                                       __HIP_MEMORY_SCOPE_AGENT);
            }
        }

        // ================= B phase (dir 1, ttime = 511-t) =================
        {
            int ttime = TLEN - 1 - t;
            const bf16* xpp = XP + (long)(ttime * 2 + 1) * 65536 + s * 2048 + (ul * 32 + b) * 4;
            u16x4 xv = *(const u16x4*)xpp;

            if (t > 0) {
                unsigned int target = (unsigned int)t;
                for (;;) {
                    unsigned int v = __hip_atomic_load(pollb, __ATOMIC_RELAXED,
                                                       __HIP_MEMORY_SCOPE_AGENT);
                    if (__all(v >= target)) break;
                    if (--guard <= 0) break;
                }
            }
            // stage h_b(t) into hsh[1]
            {
                const bf16* src = hb_b + (long)(t & 1) * 16384 + (long)tid * 32;
                f32x4 v0, v1, v2, v3;
                asm volatile(
                    "global_load_dwordx4 %0, %4, off sc0 sc1\n\t"
                    "global_load_dwordx4 %1, %4, off offset:16 sc0 sc1\n\t"
                    "global_load_dwordx4 %2, %4, off offset:32 sc0 sc1\n\t"
                    "global_load_dwordx4 %3, %4, off offset:48 sc0 sc1\n\t"
                    "s_waitcnt vmcnt(0)"
                    : "=&v"(v0), "=&v"(v1), "=&v"(v2), "=&v"(v3)
                    : "v"(src) : "memory");
                bf16* d0 = &hsh[1][sb0];
                bf16* d1 = &hsh[1][sb1];
                *(f32x4*)(d0)     = v0;
                *(f32x4*)(d0 + 8) = v1;
                *(f32x4*)(d1)     = v2;
                *(f32x4*)(d1 + 8) = v3;
            }
            __syncthreads();

            f32x4 a0 = {}, a1 = {}, a2 = {}, a3 = {};
            const bf16* hrow = &hsh[1][(nt * 16 + fr) * 520 + fq * 8];
#pragma unroll
            for (int kt = 0; kt < 16; kt += 4) {
                bf16x8 h0 = *(const bf16x8*)(hrow + (kt + 0) * 32);
                bf16x8 h1 = *(const bf16x8*)(hrow + (kt + 1) * 32);
                bf16x8 h2 = *(const bf16x8*)(hrow + (kt + 2) * 32);
                bf16x8 h3 = *(const bf16x8*)(hrow + (kt + 3) * 32);
                a0 = __builtin_amdgcn_mfma_f32_16x16x32_bf16(wAb[kt + 0], h0, a0, 0, 0, 0);
                a1 = __builtin_amdgcn_mfma_f32_16x16x32_bf16(wAb[kt + 1], h1, a1, 0, 0, 0);
                a2 = __builtin_amdgcn_mfma_f32_16x16x32_bf16(wAb[kt + 2], h2, a2, 0, 0, 0);
                a3 = __builtin_amdgcn_mfma_f32_16x16x32_bf16(wAb[kt + 3], h3, a3, 0, 0, 0);
            }
            float gi = (a0[0] + a1[0]) + (a2[0] + a3[0]) + bvb[0] + bf2f(xv.x);
            float gf = (a0[1] + a1[1]) + (a2[1] + a3[1]) + bvb[1] + bf2f(xv.y);
            float gg = (a0[2] + a1[2]) + (a2[2] + a3[2]) + bvb[2] + bf2f(xv.z);
            float go = (a0[3] + a1[3]) + (a2[3] + a3[3]) + bvb[3] + bf2f(xv.w);
            float si = sigmoid_fast(gi), sf = sigmoid_fast(gf), so = sigmoid_fast(go);
            csb = sf * csb + si * tanh_fast(gg);
            float h = so * tanh_fast(csb);

            hstage[1][b * 16 + ul] = __float2bfloat16(h);
            obuf[1][ttime & 15][tid] = h;
            __syncthreads();

            if (w == 0) {
                f32x4 hv = *(const f32x4*)&hstage[1][lane * 8];
                bf16* dst = hb_b + (long)((t + 1) & 1) * 16384 + s * 512 + lane * 8;
                asm volatile("global_store_dwordx4 %0, %1, off sc0 sc1"
                             :: "v"(dst), "v"(hv) : "memory");
                asm volatile("s_waitcnt vmcnt(0)" ::: "memory");
                if (lane == 0)
                    __hip_atomic_store(myflag_b, (unsigned int)(t + 1), __ATOMIC_RELAXED,
                                       __HIP_MEMORY_SCOPE_AGENT);
            }
        }

        // output flush every 16 steps — both dirs, off the critical path
        if ((t & 15) == 15) {
            {
                int tb = t & ~15;
                float vals[16];
#pragma unroll
                for (int c = 0; c < 16; ++c) vals[c] = obuf[0][c][tid];
                float* op = outrow_f + tb;
#pragma unroll
                for (int c4 = 0; c4 < 4; ++c4)
                    *(f32x4*)(op + c4 * 4) = *(f32x4*)&vals[c4 * 4];
            }
            {
                int tb = (TLEN - 1 - t) & ~15;
                float vals[16];
#pragma unroll
                for (int c = 0; c < 16; ++c) vals[c] = obuf[1][c][tid];
                float* op = outrow_b + tb;
#pragma unroll
                for (int c4 = 0; c4 < 4; ++c4)
                    *(f32x4*)(op + c4 * 4) = *(f32x4*)&vals[c4 * 4];
            }
        }
    }
}

extern "C" void kernel_launch(void* const* d_in, const int* in_sizes, int n_in,
                              void* d_out, int out_size, void* d_ws, size_t ws_size,
                              hipStream_t stream) {
    const float* x     = (const float*)d_in[0];
    const float* Wih_f = (const float*)d_in[1];
    const float* Whh_f = (const float*)d_in[2];
    const float* bih_f = (const float*)d_in[3];
    const float* bhh_f = (const float*)d_in[4];
    const float* Wih_b = (const float*)d_in[5];
    const float* Whh_b = (const float*)d_in[6];
    const float* bih_b = (const float*)d_in[7];
    const float* bhh_b = (const float*)d_in[8];
    float* out = (float*)d_out;

    if (ws_size < WS_REQUIRED) {
        ws_too_small_kernel<<<1, 64, 0, stream>>>(out);
        return;
    }

    char* ws = (char*)d_ws;
    bf16* XS2  = (bf16*)(ws + OFF_XS2);
    bf16* Wcat = (bf16*)(ws + OFF_WCAT);
    bf16* Whhp = (bf16*)(ws + OFF_WHHP);
    float* bias = (float*)(ws + OFF_BIAS);
    bf16* hbuf = (bf16*)(ws + OFF_HBUF);
    unsigned int* ctr   = (unsigned int*)(ws + OFF_CTR);
    unsigned int* flags = (unsigned int*)(ws + OFF_FLAG);
    bf16* XP   = (bf16*)(ws + OFF_XP);

    pack_x_kernel<<<2048, 256, 0, stream>>>(x, XS2);
    pack_w_kernel<<<2201, 256, 0, stream>>>(Wih_f, Whh_f, bih_f, bhh_f,
                                            Wih_b, Whh_b, bih_b, bhh_b,
                                            Wcat, Whhp, bias, (unsigned int*)hbuf, ctr, flags);
    gemm_xp_kernel<<<4096, 256, 0, stream>>>(Wcat, XS2, XP);
    lstm_rec_kernel<<<32, 512, 0, stream>>>(Whhp, XP, bias, hbuf, out, flags);
}

// Round 9
// 2420.616 us; speedup vs baseline: 2.4899x; 1.2357x over previous
//
#include <hip/hip_runtime.h>
#include <hip/hip_bf16.h>

// Problem constants
#define BATCH 32
#define TLEN 512
#define INCH 512
#define HID 512

typedef __bf16 bf16x8 __attribute__((ext_vector_type(8)));
typedef float f32x4 __attribute__((ext_vector_type(4)));
typedef unsigned short u16x4 __attribute__((ext_vector_type(4)));
using bf16 = __hip_bfloat16;

// ---------------- ws layout (bytes) ----------------
#define OFF_XS2   0ull                      // 16384*512*2 = 16 MiB
#define OFF_WCAT  16777216ull               // 4096*512*2  = 4 MiB
#define OFF_WHHP  20971520ull               // 2*2048*512*2 = 4 MiB
#define OFF_BIAS  25165824ull               // 2*2048*4 = 16 KiB
#define OFF_HBUF  25182208ull               // 2dir*2buf*32*512*2 = 128 KiB
#define OFF_CTR   25313280ull               // 256 B (legacy, unused)
#define OFF_FLAG  25313536ull               // 64 flags * 128 B = 8 KiB
#define OFF_XP    25321728ull               // 512*2*2048*32*2 = 128 MiB
#define WS_REQUIRED (25321728ull + 134217728ull)

__device__ __forceinline__ float sigmoid_fast(float x) {
    return 1.f / (1.f + __expf(-x));
}
__device__ __forceinline__ float tanh_fast(float x) {
    float ax = fabsf(x);
    float e = __expf(-2.f * ax);
    float r = (1.f - e) / (1.f + e);
    return copysignf(r, x);
}
__device__ __forceinline__ float bf2f(unsigned short u) {
    unsigned int i = ((unsigned int)u) << 16;
    float f; __builtin_memcpy(&f, &i, 4); return f;
}

__global__ void ws_too_small_kernel(float* out) {
    if (threadIdx.x == 0 && blockIdx.x == 0) out[0] = 12345.0f;
}

// ---------------- pack x -> XS2[(t*32+b)][k] bf16 ----------------
__global__ void pack_x_kernel(const float* __restrict__ x, bf16* __restrict__ XS2) {
    int bx = blockIdx.x;               // 2048 blocks
    int b  = bx >> 6;
    int tt = (bx >> 3) & 7;
    int kt = bx & 7;
    __shared__ float tile[64][65];
    int tid  = threadIdx.x;
    int row2 = tid >> 6;
    int col  = tid & 63;
#pragma unroll
    for (int i = 0; i < 16; ++i) {
        int row = i * 4 + row2;
        int k = kt * 64 + row;
        tile[row][col] = x[((b * 32 + (k >> 4)) * 16 + (k & 15)) * 512 + tt * 64 + col];
    }
    __syncthreads();
#pragma unroll
    for (int i = 0; i < 16; ++i) {
        int trow = i * 4 + row2;
        int t = tt * 64 + trow;
        XS2[(t * 32 + b) * 512 + kt * 64 + col] = __float2bfloat16(tile[col][trow]);
    }
}

// ---------------- pack weights / bias / zero-init ----------------
// Whhp row permutation: local row lm (0..63 per s) = ul*4 + gate:
// grow = gate*512 + s*16 + ul with gate = lm&3, ul = lm>>2.  With the MFMA
// C-layout row = fq*4+rr this puts all 4 gates of one cell into one lane's acc.
// bias repacked to [dir][s][ul][gate] f32 (float4 per cell).
__global__ void pack_w_kernel(const float* __restrict__ Wih_f, const float* __restrict__ Whh_f,
                              const float* __restrict__ bih_f, const float* __restrict__ bhh_f,
                              const float* __restrict__ Wih_b, const float* __restrict__ Whh_b,
                              const float* __restrict__ bih_b, const float* __restrict__ bhh_b,
                              bf16* __restrict__ Wcat, bf16* __restrict__ Whhp,
                              float* __restrict__ bias, unsigned int* __restrict__ hbuf32,
                              unsigned int* __restrict__ ctr, unsigned int* __restrict__ flags) {
    long idx = (long)blockIdx.x * 256 + threadIdx.x;
    if (idx < 262144) {                       // Wcat, 8-wide
        long e = idx * 8;
        int m = (int)(e >> 9), k = (int)(e & 511);
        const float* src = (m < 2048) ? &Wih_f[(long)m * 512 + k]
                                      : &Wih_b[(long)(m - 2048) * 512 + k];
        bf16* dst = &Wcat[e];
#pragma unroll
        for (int j = 0; j < 8; ++j) dst[j] = __float2bfloat16(src[j]);
        return;
    }
    idx -= 262144;
    if (idx < 262144) {                       // Whhp, 8-wide (gate-interleaved rows)
        long e = idx * 8;
        int k  = (int)(e & 511);
        int lm = (int)((e >> 9) & 63);
        int s  = (int)((e >> 15) & 31);
        int dir = (int)(e >> 20);
        int grow = (lm & 3) * 512 + s * 16 + (lm >> 2);
        const float* W = dir ? Whh_b : Whh_f;
        const float* src = &W[(long)grow * 512 + k];
        bf16* dst = &Whhp[e];
#pragma unroll
        for (int j = 0; j < 8; ++j) dst[j] = __float2bfloat16(src[j]);
        return;
    }
    idx -= 262144;
    if (idx < 4096) {                         // bias = b_ih + b_hh, [dir][s][ul][gate]
        int dir  = (int)(idx >> 11);
        int r    = (int)(idx & 2047);
        int s    = r >> 6, ul = (r >> 2) & 15, gate = r & 3;
        int g    = gate * 512 + s * 16 + ul;
        bias[idx] = (dir ? (bih_b[g] + bhh_b[g]) : (bih_f[g] + bhh_f[g]));
        return;
    }
    idx -= 4096;
    if (idx < 32768) { hbuf32[idx] = 0u; return; }  // zero h ping-pong
    idx -= 32768;
    if (idx < 64) { ctr[idx] = 0u; return; }
    idx -= 64;
    if (idx < 2048) { flags[idx] = 0u; return; }    // zero epoch flags
}

// ---------------- phase 1: XP = Wcat * XS2^T ----------------
// XP[t][dir][s][ul][b][gate] bf16 -> each lstm lane loads its 4 gates as one 8B chunk
__global__ __launch_bounds__(256, 2) void gemm_xp_kernel(const bf16* __restrict__ Wcat,
                                                         const bf16* __restrict__ XS2,
                                                         bf16* __restrict__ XP) {
    int bm = (blockIdx.x & 31) * 128;
    int bn = (blockIdx.x >> 5) * 128;
    __shared__ bf16 lA[128 * 40];
    __shared__ bf16 lB[128 * 40];
    int tid = threadIdx.x;
    int lane = tid & 63, w = tid >> 6;
    int wm = (w & 1) * 64, wn = (w >> 1) * 64;
    int fr = lane & 15, fq = lane >> 4;
    f32x4 acc[4][4] = {};
    int r = tid >> 2, c = tid & 3;
    for (int kt = 0; kt < 16; ++kt) {
        int k0 = kt * 32;
        *(bf16x8*)&lA[r * 40 + c * 8]        = *(const bf16x8*)&Wcat[(long)(bm + r) * 512 + k0 + c * 8];
        *(bf16x8*)&lA[(r + 64) * 40 + c * 8] = *(const bf16x8*)&Wcat[(long)(bm + r + 64) * 512 + k0 + c * 8];
        *(bf16x8*)&lB[r * 40 + c * 8]        = *(const bf16x8*)&XS2[(long)(bn + r) * 512 + k0 + c * 8];
        *(bf16x8*)&lB[(r + 64) * 40 + c * 8] = *(const bf16x8*)&XS2[(long)(bn + r + 64) * 512 + k0 + c * 8];
        __syncthreads();
        bf16x8 af[4], bfm[4];
#pragma unroll
        for (int i = 0; i < 4; ++i) af[i]  = *(const bf16x8*)&lA[(wm + i * 16 + fr) * 40 + fq * 8];
#pragma unroll
        for (int i = 0; i < 4; ++i) bfm[i] = *(const bf16x8*)&lB[(wn + i * 16 + fr) * 40 + fq * 8];
#pragma unroll
        for (int mi = 0; mi < 4; ++mi)
#pragma unroll
            for (int ni = 0; ni < 4; ++ni)
                acc[mi][ni] = __builtin_amdgcn_mfma_f32_16x16x32_bf16(af[mi], bfm[ni], acc[mi][ni], 0, 0, 0);
        __syncthreads();
    }
#pragma unroll
    for (int mi = 0; mi < 4; ++mi) {
#pragma unroll
        for (int rr = 0; rr < 4; ++rr) {
            int m = bm + wm + mi * 16 + fq * 4 + rr;
            int dir = m >> 11, cc = m & 2047;
            int gate = cc >> 9, u = cc & 511, s = u >> 4, ul = u & 15;
#pragma unroll
            for (int ni = 0; ni < 4; ++ni) {
                int n = bn + wn + ni * 16 + fr;
                int t = n >> 5, b = n & 31;
                long off = ((long)(t * 2 + dir) * 32 + s) * 2048 + (long)(ul * 32 + b) * 4 + gate;
                XP[off] = __float2bfloat16(acc[mi][ni][rr]);
            }
        }
    }
}

// ---------------- phase 2: bidirectional LSTM recurrence ----------------
// 32 blocks (dir, blk) x 512 threads: 16 blocks per direction, each owning
// 128 gate-rows (= 2 s-groups = 32 hidden units).  Halves the sync domain
// and the aggregate coherent traffic vs the 64-block r4 layout (r8 showed
// the overhead is contention-dominated).  Per-direction protocol mechanics
// are IDENTICAL to verified r4: sc0/sc1 staged loads, wave-1 single poller
// + LDS epoch broadcast, wave-0 contiguous coalesced store + vmcnt(0) drain
// + relaxed flag post on padded 128B lines.  No RMW atomics anywhere.
// H layout per dir: [buf][blk16][b][ul32] -> producer burst is ONE
// contiguous 2 KiB region; consumer staging is 64B/thread fully coalesced.
// Wave w: rows [w*16, w*16+16) of the block = cells ul16 = (w&3)*4+fq of
// s = blk*2 + (w>>2); each lane computes 2 cells (b=fr and b=fr+16), all
// 4 gates in-register (gate-interleaved Whhp rows).
__global__ __launch_bounds__(512, 1) void lstm_rec_kernel(const bf16* __restrict__ Whhp,
                                                          const bf16* __restrict__ XP,
                                                          const float* __restrict__ bias,
                                                          bf16* hbuf, float* out,
                                                          unsigned int* flags) {
    int bx = blockIdx.x;
    int dir = bx >> 4, blk = bx & 15;
    int tid = threadIdx.x;
    int lane = tid & 63, w = tid >> 6;      // 8 waves
    int mt = w & 3, su = w >> 2;            // row-quad within s-group, s selector
    int fr = lane & 15, fq = lane >> 4;
    int s = blk * 2 + su;
    __shared__ float obuf[16][1024];        // 64 KiB output chunk (2 cells/thread)
    __shared__ bf16  hstage[32 * 32];       // 2 KiB  h slice [b][ul32]
    __shared__ bf16  hsh[32 * 520];         // 32.5 KiB staged h [b][k], pitch 520
    __shared__ int   eps;                   // LDS epoch broadcast word

    // persistent A fragments: Whhp[dir][s][mt*16+fr][k] (rows gate-interleaved)
    const bf16* wbase = Whhp + ((long)((dir * 32 + s) * 64 + mt * 16 + fr)) * 512 + fq * 8;
    bf16x8 wA[16];
#pragma unroll
    for (int kt = 0; kt < 16; ++kt) wA[kt] = *(const bf16x8*)(wbase + kt * 32);

    int ul16 = mt * 4 + fq;                 // hidden sub-index within s
    int ul32 = su * 16 + ul16;              // hidden sub-index within block
    f32x4 bv = *(const f32x4*)&bias[((dir * 32 + s) * 16 + ul16) * 4];
    float cs0 = 0.f, cs1 = 0.f;             // cell states for b=fr, b=fr+16

    // H[dir][buf][blk][b][ul32]: per dir 2 buffers of 16384 cells (32 KiB)
    bf16* hb_dir = hbuf + (long)dir * 2 * 16384;
    unsigned int* myflag = flags + (dir * 16 + blk) * 32;             // own 128-B line
    const unsigned int* pollflag = flags + (dir * 16 + (lane & 15)) * 32;
    float* outrow0 = out + (long)fr * 524288 + (long)(dir * 512 + s * 16 + ul16) * 512;
    float* outrow1 = outrow0 + 16l * 524288;
    // staging: thread tid loads 64B (one b-row of one producer block) at cell
    // tid*32; dest hsh[(tid&31)*520 + (tid>>5)*32]  (k = blk_src*32 + ul32)
    int sbo = (tid & 31) * 520 + (tid >> 5) * 32;
    int guard = 1 << 21;

    if (tid == 0) eps = 0;
    __syncthreads();

    for (int t = 0; t < TLEN; ++t) {
        int ttime = dir ? (TLEN - 1 - t) : t;
        // xp prefetch (normal cached loads): 4 gates of both cells, 8B each
        const bf16* xpp = XP + (long)(ttime * 2 + dir) * 65536 + s * 2048 + (ul16 * 32 + fr) * 4;
        u16x4 xv0 = *(const u16x4*)xpp;
        u16x4 xv1 = *(const u16x4*)(xpp + 64);

        if (t > 0) {
            if (w == 1) {
                // wave 1: poll the 16 peer-block flags (one padded line per
                // lane&15), then broadcast the epoch via LDS
                unsigned int target = (unsigned int)t;
                for (;;) {
                    unsigned int v = __hip_atomic_load(pollflag, __ATOMIC_RELAXED,
                                                       __HIP_MEMORY_SCOPE_AGENT);
                    if (__all(v >= target)) break;
                    if (--guard <= 0) break;
                }
                if (lane == 0)
                    __hip_atomic_store(&eps, t, __ATOMIC_RELAXED,
                                       __HIP_MEMORY_SCOPE_WORKGROUP);
            } else {
                while (__hip_atomic_load(&eps, __ATOMIC_RELAXED,
                                         __HIP_MEMORY_SCOPE_WORKGROUP) < t) {
                    if (--guard <= 0) break;
                }
            }
        }

        // stage h (device-coherent, coalesced 64B per thread) into LDS [b][k]
        {
            const bf16* src = hb_dir + (long)(t & 1) * 16384 + (long)tid * 32;
            f32x4 v0, v1, v2, v3;
            asm volatile(
                "global_load_dwordx4 %0, %4, off sc0 sc1\n\t"
                "global_load_dwordx4 %1, %4, off offset:16 sc0 sc1\n\t"
                "global_load_dwordx4 %2, %4, off offset:32 sc0 sc1\n\t"
                "global_load_dwordx4 %3, %4, off offset:48 sc0 sc1\n\t"
                "s_waitcnt vmcnt(0)"
                : "=&v"(v0), "=&v"(v1), "=&v"(v2), "=&v"(v3)
                : "v"(src) : "memory");
            bf16* d = &hsh[sbo];
            *(f32x4*)(d)      = v0;
            *(f32x4*)(d + 8)  = v1;
            *(f32x4*)(d + 16) = v2;
            *(f32x4*)(d + 24) = v3;
        }
        __syncthreads();

        // B fragments from LDS; 2 batch-tiles x 2 interleaved chains, K=512
        f32x4 a0 = {}, a1 = {}, a2 = {}, a3 = {};
        const bf16* hrow0 = &hsh[fr * 520 + fq * 8];
        const bf16* hrow1 = &hsh[(16 + fr) * 520 + fq * 8];
#pragma unroll
        for (int kt = 0; kt < 16; kt += 2) {
            bf16x8 h00 = *(const bf16x8*)(hrow0 + (kt + 0) * 32);
            bf16x8 h01 = *(const bf16x8*)(hrow0 + (kt + 1) * 32);
            bf16x8 h10 = *(const bf16x8*)(hrow1 + (kt + 0) * 32);
            bf16x8 h11 = *(const bf16x8*)(hrow1 + (kt + 1) * 32);
            a0 = __builtin_amdgcn_mfma_f32_16x16x32_bf16(wA[kt + 0], h00, a0, 0, 0, 0);
            a2 = __builtin_amdgcn_mfma_f32_16x16x32_bf16(wA[kt + 0], h10, a2, 0, 0, 0);
            a1 = __builtin_amdgcn_mfma_f32_16x16x32_bf16(wA[kt + 1], h01, a1, 0, 0, 0);
            a3 = __builtin_amdgcn_mfma_f32_16x16x32_bf16(wA[kt + 1], h11, a3, 0, 0, 0);
        }

        // gates fully in-register: acc[rr] = gate rr of this lane's cells
        float gi0 = a0[0] + a1[0] + bv[0] + bf2f(xv0.x);
        float gf0 = a0[1] + a1[1] + bv[1] + bf2f(xv0.y);
        float gg0 = a0[2] + a1[2] + bv[2] + bf2f(xv0.z);
        float go0 = a0[3] + a1[3] + bv[3] + bf2f(xv0.w);
        float gi1 = a2[0] + a3[0] + bv[0] + bf2f(xv1.x);
        float gf1 = a2[1] + a3[1] + bv[1] + bf2f(xv1.y);
        float gg1 = a2[2] + a3[2] + bv[2] + bf2f(xv1.z);
        float go1 = a2[3] + a3[3] + bv[3] + bf2f(xv1.w);
        float si0 = sigmoid_fast(gi0), sf0 = sigmoid_fast(gf0), so0 = sigmoid_fast(go0);
        float si1 = sigmoid_fast(gi1), sf1 = sigmoid_fast(gf1), so1 = sigmoid_fast(go1);
        cs0 = sf0 * cs0 + si0 * tanh_fast(gg0);
        cs1 = sf1 * cs1 + si1 * tanh_fast(gg1);
        float h0 = so0 * tanh_fast(cs0);
        float h1 = so1 * tanh_fast(cs1);

        hstage[fr * 32 + ul32]        = __float2bfloat16(h0);
        hstage[(fr + 16) * 32 + ul32] = __float2bfloat16(h1);
        obuf[ttime & 15][tid]       = h0;
        obuf[ttime & 15][tid + 512] = h1;
        __syncthreads();

        // wave 0: contiguous 2 KiB coherent h store (64 x 32B, consecutive
        // lines) -> drain -> relaxed flag post
        if (w == 0) {
            f32x4 hv0 = *(const f32x4*)&hstage[lane * 16];
            f32x4 hv1 = *(const f32x4*)&hstage[lane * 16 + 8];
            bf16* dst = hb_dir + (long)((t + 1) & 1) * 16384 + blk * 1024 + lane * 16;
            asm volatile(
                "global_store_dwordx4 %0, %2, off sc0 sc1\n\t"
                "global_store_dwordx4 %1, %3, off sc0 sc1\n\t"
                "s_waitcnt vmcnt(0)"
                :: "v"(dst), "v"(dst + 8), "v"(hv0), "v"(hv1) : "memory");
            if (lane == 0)
                __hip_atomic_store(myflag, (unsigned int)(t + 1), __ATOMIC_RELAXED,
                                   __HIP_MEMORY_SCOPE_AGENT);
        }

        // output flush every 16 steps — after flag post, off the critical path
        if ((t & 15) == 15) {
            int tb = ttime & ~15;
            float vals[16];
#pragma unroll
            for (int c = 0; c < 16; ++c) vals[c] = obuf[c][tid];
            float* op = outrow0 + tb;
#pragma unroll
            for (int c4 = 0; c4 < 4; ++c4)
                *(f32x4*)(op + c4 * 4) = *(f32x4*)&vals[c4 * 4];
#pragma unroll
            for (int c = 0; c < 16; ++c) vals[c] = obuf[c][tid + 512];
            op = outrow1 + tb;
#pragma unroll
            for (int c4 = 0; c4 < 4; ++c4)
                *(f32x4*)(op + c4 * 4) = *(f32x4*)&vals[c4 * 4];
        }
    }
}

extern "C" void kernel_launch(void* const* d_in, const int* in_sizes, int n_in,
                              void* d_out, int out_size, void* d_ws, size_t ws_size,
                              hipStream_t stream) {
    const float* x     = (const float*)d_in[0];
    const float* Wih_f = (const float*)d_in[1];
    const float* Whh_f = (const float*)d_in[2];
    const float* bih_f = (const float*)d_in[3];
    const float* bhh_f = (const float*)d_in[4];
    const float* Wih_b = (const float*)d_in[5];
    const float* Whh_b = (const float*)d_in[6];
    const float* bih_b = (const float*)d_in[7];
    const float* bhh_b = (const float*)d_in[8];
    float* out = (float*)d_out;

    if (ws_size < WS_REQUIRED) {
        ws_too_small_kernel<<<1, 64, 0, stream>>>(out);
        return;
    }

    char* ws = (char*)d_ws;
    bf16* XS2  = (bf16*)(ws + OFF_XS2);
    bf16* Wcat = (bf16*)(ws + OFF_WCAT);
    bf16* Whhp = (bf16*)(ws + OFF_WHHP);
    float* bias = (float*)(ws + OFF_BIAS);
    bf16* hbuf = (bf16*)(ws + OFF_HBUF);
    unsigned int* ctr   = (unsigned int*)(ws + OFF_CTR);
    unsigned int* flags = (unsigned int*)(ws + OFF_FLAG);
    bf16* XP   = (bf16*)(ws + OFF_XP);

    pack_x_kernel<<<2048, 256, 0, stream>>>(x, XS2);
    pack_w_kernel<<<2201, 256, 0, stream>>>(Wih_f, Whh_f, bih_f, bhh_f,
                                            Wih_b, Whh_b, bih_b, bhh_b,
                                            Wcat, Whhp, bias, (unsigned int*)hbuf, ctr, flags);
    gemm_xp_kernel<<<4096, 256, 0, stream>>>(Wcat, XS2, XP);
    lstm_rec_kernel<<<32, 512, 0, stream>>>(Whhp, XP, bias, hbuf, out, flags);
}